// Round 5
// baseline (83.438 us; speedup 1.0000x reference)
//
#include <hip/hip_runtime.h>

// SoftPixelCNN as per-vertex GEMM: C[9x64] = W[9x32] * G[32x64] via mfma_f32_16x16x32_bf16.
// w_o(k) = exp(-A*||delta_k + off_o||^2)/32, A = 10*length_scale.
// Offsets (meshgrid-xy order): [0, -e1, -e0, -e2, -e3, +e3, +e2, +e0, +e1].
// Precision: hi/lo bf16 split of BOTH operands, C = Al*Bh + Ah*Bl + Ah*Bh (drop Al*Bl ~2^-16).
// Features pre-packed (prep kernel) as u32 = bf16_hi | bf16_lo<<16 so the gather lands
// directly in B-fragment layout (lane: col=l&15, k=(l>>4)*8+j).
// A-frags built via tiny per-wave LDS bounce with granule swizzle slot=(k>>2)^(o&7).

using short8 = __attribute__((ext_vector_type(8))) short;
using f32x4  = __attribute__((ext_vector_type(4))) float;
typedef unsigned int u32;

#define KNB 32
#define FDIM 64
#define ODIM 9

__device__ __forceinline__ u32 pack_hl(float x) {
    u32 b = __float_as_uint(x);
    u32 hi = b >> 16;                                  // bf16 hi (truncate)
    float r = x - __uint_as_float(hi << 16);           // residual
    return (__float_as_uint(r) & 0xFFFF0000u) | hi;    // lo<<16 | hi
}

__global__ __launch_bounds__(256) void pack_feats(const float4* __restrict__ src,
                                                  uint4* __restrict__ dst, int n4) {
    int i = blockIdx.x * 256 + threadIdx.x;
    if (i < n4) {
        float4 v = src[i];
        uint4 p;
        p.x = pack_hl(v.x); p.y = pack_hl(v.y); p.z = pack_hl(v.z); p.w = pack_hl(v.w);
        dst[i] = p;
    }
}

__global__ __launch_bounds__(256) void spcnn_mfma(
    const float* __restrict__ coords,   // (V,4)
    const u32*   __restrict__ pf,       // packed feats (V*64)
    const int*   __restrict__ nidx,     // (V,32)
    const float* __restrict__ lscale,   // (1,)
    float* __restrict__ out)            // (V,576)
{
    __shared__ __align__(16) u32 wlds[4][512];   // per-warp: 16 rows x 32 dwords (W packed)
    const int lane = threadIdx.x & 63;
    const int warp = threadIdx.x >> 6;
    const int v = blockIdx.x * 4 + warp;
    u32* vb = wlds[warp];

    const float A = 10.0f * lscale[0];
    const int myidx = nidx[v * KNB + (lane & 31)];   // lane L holds idx for k = L&31
    const int col = lane & 15;                        // B col / C col / A row
    const int grp = lane >> 4;                        // k-group: k = grp*8 + j

    // ---- B gather: frag-k indices via shfl, then all 32 dword loads (tile-major) ----
    int idxj[8];
    #pragma unroll
    for (int j = 0; j < 8; ++j) idxj[j] = __shfl(myidx, (grp << 3) + j);
    u32 boff[8];
    #pragma unroll
    for (int j = 0; j < 8; ++j) boff[j] = (u32)idxj[j] * 64u + (u32)col;
    u32 bd[4][8];
    #pragma unroll
    for (int t = 0; t < 4; ++t) {
        #pragma unroll
        for (int j = 0; j < 8; ++j)
            bd[t][j] = pf[boff[j] + t * 16];
    }
    __builtin_amdgcn_sched_barrier(0);   // keep gathers issued ahead of the weight phase

    // ---- zero W rows 9..15 so A-frag rows o>=9 read 0 ----
    if (lane < 56) ((uint4*)vb)[72 + lane] = make_uint4(0u, 0u, 0u, 0u);

    // ---- phase 1: 9 weights for k = lane&31 (all lanes compute; lanes<32 write) ----
    {
        const float4 cn = *(const float4*)(coords + (size_t)(u32)myidx * 4);
        const float4 cv = *(const float4*)(coords + (size_t)v * 4);
        const float d0 = cv.x - cn.x, d1 = cv.y - cn.y, d2 = cv.z - cn.z, d3 = cv.w - cn.w;
        const float base = d0*d0 + d1*d1 + d2*d2 + d3*d3;
        const float ex = -A * base;                 // exponent at origin offset
        const float bm = ex - A;                    // minus A*||off||^2 (=1)
        const float t0 = 2.f*A*d0, t1 = 2.f*A*d1, t2 = 2.f*A*d2, t3 = 2.f*A*d3;
        float arg[9] = {ex, bm+t1, bm+t0, bm+t2, bm+t3, bm-t3, bm-t2, bm-t0, bm-t1};
        if (lane < 32) {
            const u32 gsl = (u32)(lane >> 2);       // k-granule (4 dwords each)
            const u32 kin = (u32)(lane & 3);
            #pragma unroll
            for (int o = 0; o < ODIM; ++o) {
                // exp(arg)/32 = exp2(arg*log2e - 5); arg <= 0 -> no overflow
                float w = exp2f(fmaf(arg[o], 1.44269504f, -5.0f));
                u32 b = __float_as_uint(w);
                u32 hi = b >> 16;
                float r = w - __uint_as_float(hi << 16);
                u32 pk = (__float_as_uint(r) & 0xFFFF0000u) | hi;
                vb[o*32 + (((u32)(gsl ^ (u32)(o & 7))) << 2) + kin] = pk;
            }
        }
    }

    // ---- A frags from LDS (swizzled granules; same-wave DS is in-order) ----
    const int o = col;                               // A row for this lane
    uint4 r1 = ((const uint4*)vb)[o*8 + ((grp*2    ) ^ (o & 7))];
    uint4 r2 = ((const uint4*)vb)[o*8 + ((grp*2 + 1) ^ (o & 7))];
    union U { u32 u[4]; short8 s; };
    U AH, AL;
    AH.u[0] = (r1.x & 0xFFFFu) | (r1.y << 16);
    AH.u[1] = (r1.z & 0xFFFFu) | (r1.w << 16);
    AH.u[2] = (r2.x & 0xFFFFu) | (r2.y << 16);
    AH.u[3] = (r2.z & 0xFFFFu) | (r2.w << 16);
    AL.u[0] = (r1.x >> 16) | (r1.y & 0xFFFF0000u);
    AL.u[1] = (r1.z >> 16) | (r1.w & 0xFFFF0000u);
    AL.u[2] = (r2.x >> 16) | (r2.y & 0xFFFF0000u);
    AL.u[3] = (r2.z >> 16) | (r2.w & 0xFFFF0000u);
    short8 Ah = AH.s, Al = AL.s;

    // ---- 4 N-tiles x 3 MFMAs, accumulate f32 ----
    f32x4 acc[4];
    #pragma unroll
    for (int t = 0; t < 4; ++t) acc[t] = (f32x4){0.f, 0.f, 0.f, 0.f};
    #pragma unroll
    for (int t = 0; t < 4; ++t) {
        U BH, BL;
        #pragma unroll
        for (int p = 0; p < 4; ++p) {
            u32 e = bd[t][2*p], d = bd[t][2*p + 1];
            BH.u[p] = (e & 0xFFFFu) | (d << 16);
            BL.u[p] = (e >> 16) | (d & 0xFFFF0000u);
        }
        f32x4 a = acc[t];
        a = __builtin_amdgcn_mfma_f32_16x16x32_bf16(Al, BH.s, a, 0, 0, 0);
        a = __builtin_amdgcn_mfma_f32_16x16x32_bf16(Ah, BL.s, a, 0, 0, 0);
        a = __builtin_amdgcn_mfma_f32_16x16x32_bf16(Ah, BH.s, a, 0, 0, 0);
        acc[t] = a;
    }

    // ---- epilogue: C row = grp*4 + i, col = col; store rows 0..8 only ----
    float* orow = out + (size_t)v * (ODIM * FDIM) + (size_t)(grp * 4) * FDIM + col;
    #pragma unroll
    for (int t = 0; t < 4; ++t) {
        #pragma unroll
        for (int i = 0; i < 4; ++i) {
            if (grp * 4 + i < ODIM)
                orow[i * FDIM + t * 16] = acc[t][i];
        }
    }
}

extern "C" void kernel_launch(void* const* d_in, const int* in_sizes, int n_in,
                              void* d_out, int out_size, void* d_ws, size_t ws_size,
                              hipStream_t stream) {
    const float* coords = (const float*)d_in[0];   // (V,4) f32
    const float* feats  = (const float*)d_in[1];   // (V,64) f32
    // d_in[2] = distsq — unused on the inference path
    const int*   nb     = (const int*)d_in[3];     // (V,32) i32
    const float* ls     = (const float*)d_in[4];   // (1,) f32

    const int V  = in_sizes[0] / 4;                // 50000
    const int n4 = in_sizes[1] / 4;                // V*64/4 float4s

    u32* pf = (u32*)d_ws;                          // packed feature table (V*64*4 B)
    pack_feats<<<(n4 + 255) / 256, 256, 0, stream>>>((const float4*)feats, (uint4*)pf, n4);
    spcnn_mfma<<<V / 4, 256, 0, stream>>>(coords, pf, nb, ls, (float*)d_out);
}

// Round 6
// 43.432 us; speedup vs baseline: 1.9211x; 1.9211x over previous
//
#include <hip/hip_runtime.h>

// SoftPixelCNN: out[v, o*64+f] = (1/K) * sum_k exp(-A*d[o,v,k]) * feats[nidx[v,k], f]
// d[o,v,k] = ||(c_v + off_o) - c_n||^2 = base + 2*delta.off_o + ||off_o||^2, A = 10*length_scale.
// Offsets (meshgrid-xy order): [0, -e1, -e0, -e2, -e3, +e3, +e2, +e0, +e1].
// NUMERICS: exponentiate the COMBINED exponent (always <= 0) -> no 0*inf NaN.
// STRUCTURE (r6): kernel is TCC-fetch-bound (180MB gather misses @ ~4.2TB/s). Weights
// with max exponent < -15 contribute < 5.3*e^-15 ~ 1.6e-6 per output (threshold 2.3e-3)
// -> skip the feature gather AND the FMAs for those k via a wave-uniform ballot mask.
// Skip test is exact: maxarg over the 9 offsets = max(ex, bm + max_j |t_j|).

#define KNB 32
#define FDIM 64
#define ODIM 9

__global__ __launch_bounds__(256) void spcnn_kernel(
    const float* __restrict__ coords,   // (V,4)
    const float* __restrict__ feats,    // (V,64)
    const int*   __restrict__ nidx,     // (V,32)
    const float* __restrict__ lscale,   // (1,)
    float* __restrict__ out)            // (V,576)
{
    __shared__ float wlds[4][KNB][12];  // [warp][k][0..8] = weights (stride 12: b128-aligned)
    const int warp = threadIdx.x >> 6;
    const int lane = threadIdx.x & 63;
    const int v = blockIdx.x * 4 + warp;

    const float A = 10.0f * lscale[0];
    const int myidx = nidx[v * KNB + (lane & 31)];   // lane L holds k = L&31

    // ---- phase 1 (all lanes): exponents for my k; ballot the keep-mask ----
    const float4 cn = *(const float4*)(coords + (size_t)(unsigned)myidx * 4);
    const float4 cv = *(const float4*)(coords + (size_t)v * 4);
    const float d0 = cv.x - cn.x, d1 = cv.y - cn.y, d2 = cv.z - cn.z, d3 = cv.w - cn.w;
    const float base = d0*d0 + d1*d1 + d2*d2 + d3*d3;

    const float ex = -A * base;                 // origin-offset exponent
    const float bm = ex - A;                    // minus A*||off||^2 (=1 for axis offsets)
    const float t0 = 2.f*A*d0, t1 = 2.f*A*d1, t2 = 2.f*A*d2, t3 = 2.f*A*d3;

    const float mt = fmaxf(fmaxf(fabsf(t0), fabsf(t1)), fmaxf(fabsf(t2), fabsf(t3)));
    const float maxarg = fmaxf(ex, bm + mt);    // exact max over the 9 exponents
    const unsigned long long keep = __ballot(maxarg >= -15.0f);  // wave-uniform SGPR mask

    if (lane < 32) {
        const float s = 1.0f / (float)KNB;      // fold mean-over-K
        const float w0 = __expf(ex)      * s;
        const float w1 = __expf(bm + t1) * s;   // o = -e1
        const float w2 = __expf(bm + t0) * s;   // o = -e0
        const float w3 = __expf(bm + t2) * s;   // o = -e2
        const float w4 = __expf(bm + t3) * s;   // o = -e3
        const float w5 = __expf(bm - t3) * s;   // o = +e3
        const float w6 = __expf(bm - t2) * s;   // o = +e2
        const float w7 = __expf(bm - t0) * s;   // o = +e0
        const float w8 = __expf(bm - t1) * s;   // o = +e1
        float* wp = wlds[warp][lane];
        *(float4*)(wp)     = make_float4(w0, w1, w2, w3);
        *(float4*)(wp + 4) = make_float4(w4, w5, w6, w7);
        wp[8] = w8;
    }
    __syncthreads();

    // ---- phase 2: lane = feature f; only live neighbors touch memory/VALU ----
    float acc0=0.f,acc1=0.f,acc2=0.f,acc3=0.f,acc4=0.f,acc5=0.f,acc6=0.f,acc7=0.f,acc8=0.f;
    const float* wbase = wlds[warp][0];

    #pragma unroll
    for (int k = 0; k < KNB; ++k) {
        if (!((keep >> k) & 1ull)) continue;     // wave-uniform -> s_cbranch, no gather
        const float* wp = wbase + k * 12;
        const float4 wa = *(const float4*)wp;        // broadcast ds_read_b128
        const float4 wb = *(const float4*)(wp + 4);  // broadcast ds_read_b128
        const float w8 = wp[8];                      // broadcast ds_read_b32
        const unsigned idx = (unsigned)__builtin_amdgcn_readlane(myidx, k); // SGPR base
        const float gk = feats[(size_t)idx * FDIM + lane];  // coalesced 256B row
        acc0 = fmaf(wa.x, gk, acc0); acc1 = fmaf(wa.y, gk, acc1);
        acc2 = fmaf(wa.z, gk, acc2); acc3 = fmaf(wa.w, gk, acc3);
        acc4 = fmaf(wb.x, gk, acc4); acc5 = fmaf(wb.y, gk, acc5);
        acc6 = fmaf(wb.z, gk, acc6); acc7 = fmaf(wb.w, gk, acc7);
        acc8 = fmaf(w8,  gk, acc8);
    }

    float* op = out + (size_t)v * (ODIM * FDIM) + lane;
    op[0*FDIM] = acc0; op[1*FDIM] = acc1; op[2*FDIM] = acc2;
    op[3*FDIM] = acc3; op[4*FDIM] = acc4; op[5*FDIM] = acc5;
    op[6*FDIM] = acc6; op[7*FDIM] = acc7; op[8*FDIM] = acc8;
}

extern "C" void kernel_launch(void* const* d_in, const int* in_sizes, int n_in,
                              void* d_out, int out_size, void* d_ws, size_t ws_size,
                              hipStream_t stream) {
    const float* coords = (const float*)d_in[0];   // (V,4) f32
    const float* feats  = (const float*)d_in[1];   // (V,64) f32
    // d_in[2] = distsq — unused on the inference path
    const int*   nbidx  = (const int*)d_in[3];     // (V,32) i32
    const float* lscale = (const float*)d_in[4];   // (1,) f32

    const int V = in_sizes[0] / 4;                 // 50000
    const int blocks = V / 4;                      // 4 vertices per 256-thread block

    spcnn_kernel<<<blocks, 256, 0, stream>>>(coords, feats, nbidx, lscale, (float*)d_out);
}